// Round 3
// baseline (845.186 us; speedup 1.0000x reference)
//
#include <hip/hip_runtime.h>

// LSTMClassifier: B=2048, T=500, H1=128, H2=64, D_IN=1, FC 64->128->4.
//
// Round 3 changes vs round 2 (672 us, VALUBusy 40%, MfmaUtil 27%, VGPR=128
// (spill), bank-conflict 3.7e7):
//  - SKEWED PIPELINE, 1 barrier/step: at iter i, waves 4-7 compute h1(i)
//    (32 LSTM1 units each, 32 MFMA, 4 cells/lane) while waves 0-3 compute
//    h2(i-1) (16 LSTM2 units, 24 MFMA, 2 cells/lane). Parity: LSTM2 reads
//    h1b[prv], h2b[cur]; writes h2b[prv] -- race-free vs LSTM1's
//    read h1b[prv]/write h1b[cur].
//  - REGISTER ALIASING: LSTM1 and LSTM2 weight fragments share one
//    Wreg[8][4] array (128 VGPR) since no wave needs both -> no spill at
//    launch_bounds(512,2) (cap 256 VGPR, 2 waves/SIMD).
//  - w2h LDS buffer deleted (was the 8-way bank conflict): Whh2 frags in Wreg.
//  - log2e folded into all pre-activation weights/biases: exp() -> bare
//    v_exp_f32 (exp2), saving the 1.4427 mul per transcendental. Cell math
//    merged under common denominator: 7 trans/cell (5 exp2 + 2 rcp), exact.
//  - s_setprio(1) around MFMA clusters (role-split waves exist now -> T5).

#define B_   2048
#define T_   500
#define BM   8
#define NBLK (B_ / BM)   // 256 blocks = 1 per CU

typedef __attribute__((ext_vector_type(8))) short bf16x8;   // 8 bf16 = 4 VGPR
typedef __attribute__((ext_vector_type(4))) float f32x4;

#define LOG2E 1.44269504088896340736f

static __device__ __forceinline__ short f2bf(float f) {
  unsigned u = __builtin_bit_cast(unsigned, f);
  u = (u + 0x7fffu + ((u >> 16) & 1u)) >> 16;   // RNE
  return (short)u;
}

// Gates pre-scaled by log2e. c' = sigm(f)c + sigm(i)tanh(g); h = sigm(o)tanh(c').
// sigm(a)tanh(b) = (Eg-1)/((1+Ei)(1+Eg)); merged c-update under one rcp.
// 5 exp2 + 2 rcp = 7 transcendentals, exact algebra.
static __device__ __forceinline__ float lstm_cell_s(float gi, float gf, float gg,
                                                    float go, float& c) {
  float Ei = __builtin_amdgcn_exp2f(-gi);
  float Eg = __builtin_amdgcn_exp2f(gg + gg);
  float Ef = __builtin_amdgcn_exp2f(-gf);
  float Eo = __builtin_amdgcn_exp2f(-go);
  float t12 = (1.f + Ei) * (1.f + Eg);
  float num = c * t12 + (Eg - 1.f) * (1.f + Ef);
  c = num * __builtin_amdgcn_rcpf((1.f + Ef) * t12);
  float Ec = __builtin_amdgcn_exp2f(2.88539008177792681472f * c);  // 2*log2e*c
  return (Ec - 1.f) * __builtin_amdgcn_rcpf((1.f + Eo) * (1.f + Ec));
}

__global__ __launch_bounds__(512, 2)
void lstm_fused(const float* __restrict__ X,     // (B,1,T)
                const float* __restrict__ Wp,    // (128,1)
                const float* __restrict__ bp,    // (128)
                const float* __restrict__ Wih1,  // (512,128)
                const float* __restrict__ Whh1,  // (512,128)
                const float* __restrict__ bih1,  // (512)
                const float* __restrict__ bhh1,  // (512)
                const float* __restrict__ Wih2,  // (256,128)
                const float* __restrict__ Whh2,  // (256,64)
                const float* __restrict__ bih2,  // (256)
                const float* __restrict__ bhh2,  // (256)
                const float* __restrict__ W1,    // (128,64)
                const float* __restrict__ b1,    // (128)
                const float* __restrict__ W2,    // (4,128)
                const float* __restrict__ b2,    // (4)
                float* __restrict__ Out) {       // (B,4)
  __shared__ __align__(16) short h1b[2][16][136];  // h1 bf16 dbuf (rows 8..15 stay 0)
  __shared__ __align__(16) short h2b[2][16][72];   // h2 bf16 dbuf
  __shared__ float h2f[8][64];       // final h2 fp32 for FC head
  __shared__ float fc1s[8][132];     // fc1 activations (+4 pad)

  const int tid = threadIdx.x;
  const int ln = tid & 63;
  const int wv = tid >> 6;     // wave 0..7;  0-3 = LSTM2, 4-7 = LSTM1
  const int cl = ln & 15;      // fragment column / A-row
  const int kg = ln >> 4;      // K-group 0..3
  const int r0 = blockIdx.x * BM;
  const bool isL1 = (wv >= 4);
  const int w1 = wv - 4;       // LSTM1 wave index 0..3

  // Weight fragments -- ALIASED between roles (no wave needs both sets).
  // LSTM1 (wv>=4): Wreg[g*4+n][0..3] = Whh1 frags, units 32*w1+16g+cl, gate n.
  // LSTM2 (wv<4):  Wreg[n][0..3] = Wih2 frags; Wreg[4+n][0..1] = Whh2 frags.
  bf16x8 Wreg[8][4];
  float uv[16];   // LSTM1: uv[0..7]=u1 (x coef), uv[8..15]=v1 (bias). LSTM2: uv[0..3]=bias.

  // ---------------- one-time setup (weights pre-scaled by log2e) ----------
  if (isL1) {
#pragma unroll
    for (int g = 0; g < 2; ++g) {
#pragma unroll
      for (int n = 0; n < 4; ++n) {
        const int R = n * 128 + 32 * w1 + 16 * g + cl;
        float u = 0.f, vv = bih1[R] + bhh1[R];
        const float4* Wi4 = (const float4*)(Wih1 + R * 128);
        const float4* Wp4 = (const float4*)Wp;
        const float4* bp4 = (const float4*)bp;
#pragma unroll 4
        for (int d = 0; d < 32; ++d) {
          float4 a = Wi4[d], pw = Wp4[d], qb = bp4[d];
          u  += a.x*pw.x + a.y*pw.y + a.z*pw.z + a.w*pw.w;
          vv += a.x*qb.x + a.y*qb.y + a.z*qb.z + a.w*qb.w;
        }
        uv[g * 4 + n] = u * LOG2E;
        uv[8 + g * 4 + n] = vv * LOG2E;
#pragma unroll
        for (int kf = 0; kf < 4; ++kf) {
          const float4* s4 = (const float4*)(Whh1 + R * 128 + kf * 32 + kg * 8);
          float4 a0 = s4[0], a1 = s4[1];
          bf16x8 fr;
          fr[0]=f2bf(a0.x*LOG2E); fr[1]=f2bf(a0.y*LOG2E);
          fr[2]=f2bf(a0.z*LOG2E); fr[3]=f2bf(a0.w*LOG2E);
          fr[4]=f2bf(a1.x*LOG2E); fr[5]=f2bf(a1.y*LOG2E);
          fr[6]=f2bf(a1.z*LOG2E); fr[7]=f2bf(a1.w*LOG2E);
          Wreg[g * 4 + n][kf] = fr;
        }
      }
    }
  } else {
#pragma unroll
    for (int n = 0; n < 4; ++n) {
      const int R = n * 64 + 16 * wv + cl;
      uv[n] = (bih2[R] + bhh2[R]) * LOG2E;
#pragma unroll
      for (int kf = 0; kf < 4; ++kf) {
        const float4* s4 = (const float4*)(Wih2 + R * 128 + kf * 32 + kg * 8);
        float4 a0 = s4[0], a1 = s4[1];
        bf16x8 fr;
        fr[0]=f2bf(a0.x*LOG2E); fr[1]=f2bf(a0.y*LOG2E);
        fr[2]=f2bf(a0.z*LOG2E); fr[3]=f2bf(a0.w*LOG2E);
        fr[4]=f2bf(a1.x*LOG2E); fr[5]=f2bf(a1.y*LOG2E);
        fr[6]=f2bf(a1.z*LOG2E); fr[7]=f2bf(a1.w*LOG2E);
        Wreg[n][kf] = fr;
      }
#pragma unroll
      for (int kf = 0; kf < 2; ++kf) {
        const float4* s4 = (const float4*)(Whh2 + R * 64 + kf * 32 + kg * 8);
        float4 a0 = s4[0], a1 = s4[1];
        bf16x8 fr;
        fr[0]=f2bf(a0.x*LOG2E); fr[1]=f2bf(a0.y*LOG2E);
        fr[2]=f2bf(a0.z*LOG2E); fr[3]=f2bf(a0.w*LOG2E);
        fr[4]=f2bf(a1.x*LOG2E); fr[5]=f2bf(a1.y*LOG2E);
        fr[6]=f2bf(a1.z*LOG2E); fr[7]=f2bf(a1.w*LOG2E);
        Wreg[4 + n][kf] = fr;
      }
    }
  }

  // zero both h-state buffers (rows 8..15 must stay zero forever)
  for (int i = tid; i < 2 * 16 * 136; i += 512) ((short*)h1b)[i] = 0;
  for (int i = tid; i < 2 * 16 * 72;  i += 512) ((short*)h2b)[i] = 0;
  __syncthreads();

  // per-lane persistent state
  float cA = 0.f, cB = 0.f, cA2 = 0.f, cB2 = 0.f;  // cells: LSTM1 groups 0,1 / LSTM2
  const int rA = (kg < 2) ? kg * 4 : (kg - 2) * 4 + 2;   // redistributed rows
  const int rB = rA + 1;

  float xr[4];
#pragma unroll
  for (int e = 0; e < 4; ++e)
    xr[e] = (isL1 && kg < 2) ? X[(size_t)(r0 + kg * 4 + e) * T_ + 0] : 0.f;

  // ---------------- the scan: iter i -> h1(i) [waves 4-7] + h2(i-1) [0-3] --
  for (int i = 0; i <= T_; ++i) {
    const int cur = i & 1, prv = cur ^ 1;

    if (isL1) {
      if (i < T_) {
        bf16x8 a1[4];
#pragma unroll
        for (int kf = 0; kf < 4; ++kf)
          a1[kf] = *(const bf16x8*)&h1b[prv][cl][kf * 32 + kg * 8];

        f32x4 acc[2][4];
#pragma unroll
        for (int g = 0; g < 2; ++g)
#pragma unroll
          for (int n = 0; n < 4; ++n) {
            f32x4 a;
#pragma unroll
            for (int e = 0; e < 4; ++e)
              a[e] = xr[e] * uv[g * 4 + n] + uv[8 + g * 4 + n];
            acc[g][n] = a;
          }
        __builtin_amdgcn_s_setprio(1);
#pragma unroll
        for (int g = 0; g < 2; ++g)
#pragma unroll
          for (int n = 0; n < 4; ++n)
#pragma unroll
            for (int kf = 0; kf < 4; ++kf)
              acc[g][n] = __builtin_amdgcn_mfma_f32_16x16x32_bf16(
                  a1[kf], Wreg[g * 4 + n][kf], acc[g][n], 0, 0, 0);
        __builtin_amdgcn_s_setprio(0);

        // prefetch x for next step (clamped; rows valid only for kg<2)
        if (kg < 2) {
          const int tn = (i + 1 < T_) ? i + 1 : T_ - 1;
#pragma unroll
          for (int e = 0; e < 4; ++e)
            xr[e] = X[(size_t)(r0 + kg * 4 + e) * T_ + tn];
        }

#pragma unroll
        for (int g = 0; g < 2; ++g) {
          float gA[4], gB[4];
#pragma unroll
          for (int n = 0; n < 4; ++n) {
            float s2 = __shfl_xor(acc[g][n][2], 32);
            float s3 = __shfl_xor(acc[g][n][3], 32);
            gA[n] = (kg < 2) ? acc[g][n][0] : s2;
            gB[n] = (kg < 2) ? acc[g][n][1] : s3;
          }
          float& cg = (g == 0) ? cA : cB;
          float hA, hB;
          {
            float c0 = cg;  // two independent cells; keep chains separate
            hA = lstm_cell_s(gA[0], gA[1], gA[2], gA[3], c0);
            cg = c0;
          }
          {
            float c1 = (g == 0) ? cA2 : cB2;   // reuse alias trick below
            (void)c1;
            hB = 0.f;
          }
          // NOTE: cells for rB rows need their own carry; handled explicitly:
          static_assert(true, "");
          (void)hB;
          // -- replaced below --
          float cB_local = (g == 0) ? cA2 : cB2;
          hB = lstm_cell_s(gB[0], gB[1], gB[2], gB[3], cB_local);
          if (g == 0) cA2 = cB_local; else cB2 = cB_local;

          const int uu = 32 * w1 + 16 * g + cl;
          h1b[cur][rA][uu] = f2bf(hA);
          h1b[cur][rB][uu] = f2bf(hB);
        }
      }
    } else {
      if (i > 0) {
        bf16x8 ah[4], ag[2];
#pragma unroll
        for (int kf = 0; kf < 4; ++kf)
          ah[kf] = *(const bf16x8*)&h1b[prv][cl][kf * 32 + kg * 8];
#pragma unroll
        for (int kf = 0; kf < 2; ++kf)
          ag[kf] = *(const bf16x8*)&h2b[cur][cl][kf * 32 + kg * 8];

        f32x4 acc2[4];
#pragma unroll
        for (int n = 0; n < 4; ++n)
          acc2[n] = (f32x4){uv[n], uv[n], uv[n], uv[n]};
        __builtin_amdgcn_s_setprio(1);
#pragma unroll
        for (int n = 0; n < 4; ++n) {
#pragma unroll
          for (int kf = 0; kf < 2; ++kf)
            acc2[n] = __builtin_amdgcn_mfma_f32_16x16x32_bf16(
                ag[kf], Wreg[4 + n][kf], acc2[n], 0, 0, 0);
#pragma unroll
          for (int kf = 0; kf < 4; ++kf)
            acc2[n] = __builtin_amdgcn_mfma_f32_16x16x32_bf16(
                ah[kf], Wreg[n][kf], acc2[n], 0, 0, 0);
        }
        __builtin_amdgcn_s_setprio(0);

        float gA[4], gB[4];
#pragma unroll
        for (int n = 0; n < 4; ++n) {
          float s2 = __shfl_xor(acc2[n][2], 32);
          float s3 = __shfl_xor(acc2[n][3], 32);
          gA[n] = (kg < 2) ? acc2[n][0] : s2;
          gB[n] = (kg < 2) ? acc2[n][1] : s3;
        }
        float hA = lstm_cell_s(gA[0], gA[1], gA[2], gA[3], cA2);
        float hB = lstm_cell_s(gB[0], gB[1], gB[2], gB[3], cB2);
        const int uu = 16 * wv + cl;
        h2b[prv][rA][uu] = f2bf(hA);   // h2(i-1) lives at parity (i-1)&1 = prv
        h2b[prv][rB][uu] = f2bf(hB);
        if (i == T_) { h2f[rA][uu] = hA; h2f[rB][uu] = hB; }
      }
    }
    __syncthreads();   // publish h1(i) and h2(i-1)
  }

  // ---------------- FC head (fp32) ----------------
  // fc1: (8 x 64) @ (64 x 128) + b1, relu
  {
    const int u = tid & 127, r2 = tid >> 7;   // r2 0..3 -> rows 2r2, 2r2+1
    float a0 = b1[u], a1f = b1[u];
    for (int k = 0; k < 64; ++k) {
      float w = W1[u * 64 + k];
      a0  += h2f[r2 * 2 + 0][k] * w;
      a1f += h2f[r2 * 2 + 1][k] * w;
    }
    fc1s[r2 * 2 + 0][u] = fmaxf(a0, 0.f);
    fc1s[r2 * 2 + 1][u] = fmaxf(a1f, 0.f);
  }
  __syncthreads();
  // fc2: (8 x 128) @ (128 x 4) + b2
  if (tid < 32) {
    const int r = tid >> 2, cls = tid & 3;
    float a = b2[cls];
    for (int k = 0; k < 128; ++k) a += fc1s[r][k] * W2[cls * 128 + k];
    Out[(size_t)(r0 + r) * 4 + cls] = a;
  }
}

extern "C" void kernel_launch(void* const* d_in, const int* in_sizes, int n_in,
                              void* d_out, int out_size, void* d_ws, size_t ws_size,
                              hipStream_t stream) {
  const float* X    = (const float*)d_in[0];
  const float* Wp   = (const float*)d_in[1];
  const float* bp   = (const float*)d_in[2];
  const float* Wih1 = (const float*)d_in[3];
  const float* Whh1 = (const float*)d_in[4];
  const float* bih1 = (const float*)d_in[5];
  const float* bhh1 = (const float*)d_in[6];
  const float* Wih2 = (const float*)d_in[7];
  const float* Whh2 = (const float*)d_in[8];
  const float* bih2 = (const float*)d_in[9];
  const float* bhh2 = (const float*)d_in[10];
  const float* W1   = (const float*)d_in[11];
  const float* b1   = (const float*)d_in[12];
  const float* W2   = (const float*)d_in[13];
  const float* b2   = (const float*)d_in[14];
  float* Out = (float*)d_out;

  hipLaunchKernelGGL(lstm_fused, dim3(NBLK), dim3(512), 0, stream,
                     X, Wp, bp, Wih1, Whh1, bih1, bhh1,
                     Wih2, Whh2, bih2, bhh2, W1, b1, W2, b2, Out);
}

// Round 4
// 842.310 us; speedup vs baseline: 1.0034x; 1.0034x over previous
//
#include <hip/hip_runtime.h>

// LSTMClassifier: B=2048, T=500, H1=128, H2=64, D_IN=1, FC 64->128->4.
//
// Round 4 = Round 3 structure + THE SPILL FIX.
// R3 evidence: VGPR_Count=128 while Wreg alone needs 128 -> ~90 regs/lane
// spilled; WRITE_SIZE 4.6->30.5 MB (scratch traffic). Cause:
// __launch_bounds__(512, 2): hipcc arg2 = min BLOCKS per CU (CUDA semantics),
// 2 blocks x 8 waves = 4 waves/SIMD -> VGPR cap 128. Fix: (512, 1) ->
// 2 waves/SIMD -> cap 256. Demand ~215 -> no spill, same occupancy
// (1 block/CU was all we wanted).
//
// Structure (from R3):
//  - Skewed pipeline, 1 barrier/step: iter i, waves 4-7 compute h1(i)
//    (32 LSTM1 units each, 32 MFMA, 4 cells/lane), waves 0-3 compute h2(i-1)
//    (16 LSTM2 units, 24 MFMA, 2 cells/lane). Parity: LSTM2 reads h1b[prv],
//    h2b[cur], writes h2b[prv] -- race-free.
//  - Weight frags aliased in one Wreg[8][4] (no wave needs both sets).
//  - log2e pre-folded into weights/biases -> bare v_exp_f32; cell merged
//    under common denominators: 5 exp2 + 2 rcp per cell, exact algebra.
//  - s_setprio(1) around MFMA clusters (role-split waves share a SIMD).

#define B_   2048
#define T_   500
#define BM   8
#define NBLK (B_ / BM)   // 256 blocks = 1 per CU

typedef __attribute__((ext_vector_type(8))) short bf16x8;   // 8 bf16 = 4 VGPR
typedef __attribute__((ext_vector_type(4))) float f32x4;

#define LOG2E 1.44269504088896340736f

static __device__ __forceinline__ short f2bf(float f) {
  unsigned u = __builtin_bit_cast(unsigned, f);
  u = (u + 0x7fffu + ((u >> 16) & 1u)) >> 16;   // RNE
  return (short)u;
}

// Gates pre-scaled by log2e. c' = sigm(f)c + sigm(i)tanh(g); h = sigm(o)tanh(c').
// sigm(a)tanh(b) = (Eg-1)/((1+Ei)(1+Eg)); merged c-update under one rcp.
// 5 exp2 + 2 rcp = 7 transcendentals, exact algebra.
static __device__ __forceinline__ float lstm_cell_s(float gi, float gf, float gg,
                                                    float go, float& c) {
  float Ei = __builtin_amdgcn_exp2f(-gi);
  float Eg = __builtin_amdgcn_exp2f(gg + gg);
  float Ef = __builtin_amdgcn_exp2f(-gf);
  float Eo = __builtin_amdgcn_exp2f(-go);
  float t12 = (1.f + Ei) * (1.f + Eg);
  float num = c * t12 + (Eg - 1.f) * (1.f + Ef);
  c = num * __builtin_amdgcn_rcpf((1.f + Ef) * t12);
  float Ec = __builtin_amdgcn_exp2f(2.88539008177792681472f * c);  // 2*log2e*c
  return (Ec - 1.f) * __builtin_amdgcn_rcpf((1.f + Eo) * (1.f + Ec));
}

__global__ __launch_bounds__(512, 1)   // <= THE FIX: 1 block/CU, VGPR cap 256
void lstm_fused(const float* __restrict__ X,     // (B,1,T)
                const float* __restrict__ Wp,    // (128,1)
                const float* __restrict__ bp,    // (128)
                const float* __restrict__ Wih1,  // (512,128)
                const float* __restrict__ Whh1,  // (512,128)
                const float* __restrict__ bih1,  // (512)
                const float* __restrict__ bhh1,  // (512)
                const float* __restrict__ Wih2,  // (256,128)
                const float* __restrict__ Whh2,  // (256,64)
                const float* __restrict__ bih2,  // (256)
                const float* __restrict__ bhh2,  // (256)
                const float* __restrict__ W1,    // (128,64)
                const float* __restrict__ b1,    // (128)
                const float* __restrict__ W2,    // (4,128)
                const float* __restrict__ b2,    // (4)
                float* __restrict__ Out) {       // (B,4)
  __shared__ __align__(16) short h1b[2][16][136];  // h1 bf16 dbuf (rows 8..15 stay 0)
  __shared__ __align__(16) short h2b[2][16][72];   // h2 bf16 dbuf
  __shared__ float h2f[8][64];       // final h2 fp32 for FC head
  __shared__ float fc1s[8][132];     // fc1 activations (+4 pad)

  const int tid = threadIdx.x;
  const int ln = tid & 63;
  const int wv = tid >> 6;     // wave 0..7;  0-3 = LSTM2, 4-7 = LSTM1
  const int cl = ln & 15;      // fragment column / A-row
  const int kg = ln >> 4;      // K-group 0..3
  const int r0 = blockIdx.x * BM;
  const bool isL1 = (wv >= 4);
  const int w1 = wv - 4;       // LSTM1 wave index 0..3

  // Weight fragments -- ALIASED between roles (no wave needs both sets).
  // LSTM1 (wv>=4): Wreg[g*4+n][0..3] = Whh1 frags, units 32*w1+16g+cl, gate n.
  // LSTM2 (wv<4):  Wreg[n][0..3] = Wih2 frags; Wreg[4+n][0..1] = Whh2 frags.
  bf16x8 Wreg[8][4];
  float uv[16];   // LSTM1: uv[0..7]=u1*log2e, uv[8..15]=v1*log2e. LSTM2: uv[0..3]=bias*log2e.

  // ---------------- one-time setup (weights pre-scaled by log2e) ----------
  if (isL1) {
#pragma unroll
    for (int g = 0; g < 2; ++g) {
#pragma unroll
      for (int n = 0; n < 4; ++n) {
        const int R = n * 128 + 32 * w1 + 16 * g + cl;
        float u = 0.f, vv = bih1[R] + bhh1[R];
        const float4* Wi4 = (const float4*)(Wih1 + R * 128);
        const float4* Wp4 = (const float4*)Wp;
        const float4* bp4 = (const float4*)bp;
#pragma unroll 4
        for (int d = 0; d < 32; ++d) {
          float4 a = Wi4[d], pw = Wp4[d], qb = bp4[d];
          u  += a.x*pw.x + a.y*pw.y + a.z*pw.z + a.w*pw.w;
          vv += a.x*qb.x + a.y*qb.y + a.z*qb.z + a.w*qb.w;
        }
        uv[g * 4 + n] = u * LOG2E;
        uv[8 + g * 4 + n] = vv * LOG2E;
#pragma unroll
        for (int kf = 0; kf < 4; ++kf) {
          const float4* s4 = (const float4*)(Whh1 + R * 128 + kf * 32 + kg * 8);
          float4 a0 = s4[0], a1 = s4[1];
          bf16x8 fr;
          fr[0]=f2bf(a0.x*LOG2E); fr[1]=f2bf(a0.y*LOG2E);
          fr[2]=f2bf(a0.z*LOG2E); fr[3]=f2bf(a0.w*LOG2E);
          fr[4]=f2bf(a1.x*LOG2E); fr[5]=f2bf(a1.y*LOG2E);
          fr[6]=f2bf(a1.z*LOG2E); fr[7]=f2bf(a1.w*LOG2E);
          Wreg[g * 4 + n][kf] = fr;
        }
      }
    }
  } else {
#pragma unroll
    for (int n = 0; n < 4; ++n) {
      const int R = n * 64 + 16 * wv + cl;
      uv[n] = (bih2[R] + bhh2[R]) * LOG2E;
#pragma unroll
      for (int kf = 0; kf < 4; ++kf) {
        const float4* s4 = (const float4*)(Wih2 + R * 128 + kf * 32 + kg * 8);
        float4 a0 = s4[0], a1 = s4[1];
        bf16x8 fr;
        fr[0]=f2bf(a0.x*LOG2E); fr[1]=f2bf(a0.y*LOG2E);
        fr[2]=f2bf(a0.z*LOG2E); fr[3]=f2bf(a0.w*LOG2E);
        fr[4]=f2bf(a1.x*LOG2E); fr[5]=f2bf(a1.y*LOG2E);
        fr[6]=f2bf(a1.z*LOG2E); fr[7]=f2bf(a1.w*LOG2E);
        Wreg[n][kf] = fr;
      }
#pragma unroll
      for (int kf = 0; kf < 2; ++kf) {
        const float4* s4 = (const float4*)(Whh2 + R * 64 + kf * 32 + kg * 8);
        float4 a0 = s4[0], a1 = s4[1];
        bf16x8 fr;
        fr[0]=f2bf(a0.x*LOG2E); fr[1]=f2bf(a0.y*LOG2E);
        fr[2]=f2bf(a0.z*LOG2E); fr[3]=f2bf(a0.w*LOG2E);
        fr[4]=f2bf(a1.x*LOG2E); fr[5]=f2bf(a1.y*LOG2E);
        fr[6]=f2bf(a1.z*LOG2E); fr[7]=f2bf(a1.w*LOG2E);
        Wreg[4 + n][kf] = fr;
      }
    }
  }

  // zero both h-state buffers (rows 8..15 must stay zero forever)
  for (int i = tid; i < 2 * 16 * 136; i += 512) ((short*)h1b)[i] = 0;
  for (int i = tid; i < 2 * 16 * 72;  i += 512) ((short*)h2b)[i] = 0;
  __syncthreads();

  // per-lane persistent state.
  // LSTM1 wave: 4 cells/lane -> carries (g0,rA)=cA (g0,rB)=cA2 (g1,rA)=cB (g1,rB)=cB2.
  // LSTM2 wave: 2 cells/lane -> carries cA2 (rA), cB2 (rB).
  float cA = 0.f, cB = 0.f, cA2 = 0.f, cB2 = 0.f;
  const int rA = (kg < 2) ? kg * 4 : (kg - 2) * 4 + 2;   // redistributed rows
  const int rB = rA + 1;

  float xr[4];
#pragma unroll
  for (int e = 0; e < 4; ++e)
    xr[e] = (isL1 && kg < 2) ? X[(size_t)(r0 + kg * 4 + e) * T_ + 0] : 0.f;

  // ---------------- the scan: iter i -> h1(i) [waves 4-7] + h2(i-1) [0-3] --
  for (int i = 0; i <= T_; ++i) {
    const int cur = i & 1, prv = cur ^ 1;

    if (isL1) {
      if (i < T_) {
        bf16x8 a1[4];
#pragma unroll
        for (int kf = 0; kf < 4; ++kf)
          a1[kf] = *(const bf16x8*)&h1b[prv][cl][kf * 32 + kg * 8];

        f32x4 acc[2][4];
#pragma unroll
        for (int g = 0; g < 2; ++g)
#pragma unroll
          for (int n = 0; n < 4; ++n) {
            f32x4 a;
#pragma unroll
            for (int e = 0; e < 4; ++e)
              a[e] = xr[e] * uv[g * 4 + n] + uv[8 + g * 4 + n];
            acc[g][n] = a;
          }
        __builtin_amdgcn_s_setprio(1);
#pragma unroll
        for (int g = 0; g < 2; ++g)
#pragma unroll
          for (int n = 0; n < 4; ++n)
#pragma unroll
            for (int kf = 0; kf < 4; ++kf)
              acc[g][n] = __builtin_amdgcn_mfma_f32_16x16x32_bf16(
                  a1[kf], Wreg[g * 4 + n][kf], acc[g][n], 0, 0, 0);
        __builtin_amdgcn_s_setprio(0);

        // prefetch x for next step (clamped; rows valid only for kg<2)
        if (kg < 2) {
          const int tn = (i + 1 < T_) ? i + 1 : T_ - 1;
#pragma unroll
          for (int e = 0; e < 4; ++e)
            xr[e] = X[(size_t)(r0 + kg * 4 + e) * T_ + tn];
        }

#pragma unroll
        for (int g = 0; g < 2; ++g) {
          float gA[4], gB[4];
#pragma unroll
          for (int n = 0; n < 4; ++n) {
            float s2 = __shfl_xor(acc[g][n][2], 32);
            float s3 = __shfl_xor(acc[g][n][3], 32);
            gA[n] = (kg < 2) ? acc[g][n][0] : s2;
            gB[n] = (kg < 2) ? acc[g][n][1] : s3;
          }
          float crA = (g == 0) ? cA : cB;
          float crB = (g == 0) ? cA2 : cB2;
          float hA = lstm_cell_s(gA[0], gA[1], gA[2], gA[3], crA);
          float hB = lstm_cell_s(gB[0], gB[1], gB[2], gB[3], crB);
          if (g == 0) { cA = crA; cA2 = crB; } else { cB = crA; cB2 = crB; }

          const int uu = 32 * w1 + 16 * g + cl;
          h1b[cur][rA][uu] = f2bf(hA);
          h1b[cur][rB][uu] = f2bf(hB);
        }
      }
    } else {
      if (i > 0) {
        bf16x8 ah[4], ag[2];
#pragma unroll
        for (int kf = 0; kf < 4; ++kf)
          ah[kf] = *(const bf16x8*)&h1b[prv][cl][kf * 32 + kg * 8];
#pragma unroll
        for (int kf = 0; kf < 2; ++kf)
          ag[kf] = *(const bf16x8*)&h2b[cur][cl][kf * 32 + kg * 8];

        f32x4 acc2[4];
#pragma unroll
        for (int n = 0; n < 4; ++n)
          acc2[n] = (f32x4){uv[n], uv[n], uv[n], uv[n]};
        __builtin_amdgcn_s_setprio(1);
#pragma unroll
        for (int n = 0; n < 4; ++n) {
#pragma unroll
          for (int kf = 0; kf < 2; ++kf)
            acc2[n] = __builtin_amdgcn_mfma_f32_16x16x32_bf16(
                ag[kf], Wreg[4 + n][kf], acc2[n], 0, 0, 0);
#pragma unroll
          for (int kf = 0; kf < 4; ++kf)
            acc2[n] = __builtin_amdgcn_mfma_f32_16x16x32_bf16(
                ah[kf], Wreg[n][kf], acc2[n], 0, 0, 0);
        }
        __builtin_amdgcn_s_setprio(0);

        float gA[4], gB[4];
#pragma unroll
        for (int n = 0; n < 4; ++n) {
          float s2 = __shfl_xor(acc2[n][2], 32);
          float s3 = __shfl_xor(acc2[n][3], 32);
          gA[n] = (kg < 2) ? acc2[n][0] : s2;
          gB[n] = (kg < 2) ? acc2[n][1] : s3;
        }
        float hA = lstm_cell_s(gA[0], gA[1], gA[2], gA[3], cA2);
        float hB = lstm_cell_s(gB[0], gB[1], gB[2], gB[3], cB2);
        const int uu = 16 * wv + cl;
        h2b[prv][rA][uu] = f2bf(hA);   // h2(i-1) lives at parity (i-1)&1 = prv
        h2b[prv][rB][uu] = f2bf(hB);
        if (i == T_) { h2f[rA][uu] = hA; h2f[rB][uu] = hB; }
      }
    }
    __syncthreads();   // publish h1(i) and h2(i-1)
  }

  // ---------------- FC head (fp32) ----------------
  // fc1: (8 x 64) @ (64 x 128) + b1, relu
  {
    const int u = tid & 127, r2 = tid >> 7;   // r2 0..3 -> rows 2r2, 2r2+1
    float a0 = b1[u], a1f = b1[u];
    for (int k = 0; k < 64; ++k) {
      float w = W1[u * 64 + k];
      a0  += h2f[r2 * 2 + 0][k] * w;
      a1f += h2f[r2 * 2 + 1][k] * w;
    }
    fc1s[r2 * 2 + 0][u] = fmaxf(a0, 0.f);
    fc1s[r2 * 2 + 1][u] = fmaxf(a1f, 0.f);
  }
  __syncthreads();
  // fc2: (8 x 128) @ (128 x 4) + b2
  if (tid < 32) {
    const int r = tid >> 2, cls = tid & 3;
    float a = b2[cls];
    for (int k = 0; k < 128; ++k) a += fc1s[r][k] * W2[cls * 128 + k];
    Out[(size_t)(r0 + r) * 4 + cls] = a;
  }
}

extern "C" void kernel_launch(void* const* d_in, const int* in_sizes, int n_in,
                              void* d_out, int out_size, void* d_ws, size_t ws_size,
                              hipStream_t stream) {
  const float* X    = (const float*)d_in[0];
  const float* Wp   = (const float*)d_in[1];
  const float* bp   = (const float*)d_in[2];
  const float* Wih1 = (const float*)d_in[3];
  const float* Whh1 = (const float*)d_in[4];
  const float* bih1 = (const float*)d_in[5];
  const float* bhh1 = (const float*)d_in[6];
  const float* Wih2 = (const float*)d_in[7];
  const float* Whh2 = (const float*)d_in[8];
  const float* bih2 = (const float*)d_in[9];
  const float* bhh2 = (const float*)d_in[10];
  const float* W1   = (const float*)d_in[11];
  const float* b1   = (const float*)d_in[12];
  const float* W2   = (const float*)d_in[13];
  const float* b2   = (const float*)d_in[14];
  float* Out = (float*)d_out;

  hipLaunchKernelGGL(lstm_fused, dim3(NBLK), dim3(512), 0, stream,
                     X, Wp, bp, Wih1, Whh1, bih1, bhh1,
                     Wih2, Whh2, bih2, bhh2, W1, b1, W2, b2, Out);
}

// Round 5
// 779.257 us; speedup vs baseline: 1.0846x; 1.0809x over previous
//
#include <hip/hip_runtime.h>

// LSTMClassifier: B=2048, T=500, H1=128, H2=64, D_IN=1, FC 64->128->4.
//
// Round 5 = Round 3/4 structure + REAL spill fix via backend attributes.
// Evidence R3/R4: VGPR_Count pinned at 128 under BOTH __launch_bounds__(512,2)
// and (512,1); WRITE_SIZE 30.5MB = Wreg spilled at setup and reloaded from
// scratch (via L1/L2, invisible in FETCH_SIZE) every step -> ~3000 extra
// cyc/step. hipcc's occupancy heuristic targets 4 waves/EU regardless of the
// launch_bounds hint. Fix: pin it directly:
//   amdgpu_flat_work_group_size(512,512) + amdgpu_waves_per_eu(2,2)
// -> VGPR budget 512/2 = 256 >= demand (~215) -> no spill, occupancy
// unchanged (we run exactly 8 waves = 2/EU per CU).
//
// Structure (unchanged from R3/R4):
//  - Skewed pipeline, 1 barrier/step: iter i, waves 4-7 compute h1(i)
//    (32 LSTM1 units each, 32 MFMA, 4 cells/lane), waves 0-3 compute h2(i-1)
//    (16 LSTM2 units, 24 MFMA, 2 cells/lane). Parity: LSTM2 reads h1b[prv],
//    h2b[cur], writes h2b[prv] -- race-free.
//  - Weight frags aliased in one Wreg[8][4] (no wave needs both sets).
//  - log2e pre-folded into weights/biases -> bare v_exp_f32; cell merged
//    under common denominators: 5 exp2 + 2 rcp per cell, exact algebra.
//  - s_setprio(1) around MFMA clusters (role-split waves share a SIMD).

#define B_   2048
#define T_   500
#define BM   8
#define NBLK (B_ / BM)   // 256 blocks = 1 per CU

typedef __attribute__((ext_vector_type(8))) short bf16x8;   // 8 bf16 = 4 VGPR
typedef __attribute__((ext_vector_type(4))) float f32x4;

#define LOG2E 1.44269504088896340736f

static __device__ __forceinline__ short f2bf(float f) {
  unsigned u = __builtin_bit_cast(unsigned, f);
  u = (u + 0x7fffu + ((u >> 16) & 1u)) >> 16;   // RNE
  return (short)u;
}

// Gates pre-scaled by log2e. c' = sigm(f)c + sigm(i)tanh(g); h = sigm(o)tanh(c').
// sigm(a)tanh(b) = (Eg-1)/((1+Ei)(1+Eg)); merged c-update under one rcp.
// 5 exp2 + 2 rcp = 7 transcendentals, exact algebra.
static __device__ __forceinline__ float lstm_cell_s(float gi, float gf, float gg,
                                                    float go, float& c) {
  float Ei = __builtin_amdgcn_exp2f(-gi);
  float Eg = __builtin_amdgcn_exp2f(gg + gg);
  float Ef = __builtin_amdgcn_exp2f(-gf);
  float Eo = __builtin_amdgcn_exp2f(-go);
  float t12 = (1.f + Ei) * (1.f + Eg);
  float num = c * t12 + (Eg - 1.f) * (1.f + Ef);
  c = num * __builtin_amdgcn_rcpf((1.f + Ef) * t12);
  float Ec = __builtin_amdgcn_exp2f(2.88539008177792681472f * c);  // 2*log2e*c
  return (Ec - 1.f) * __builtin_amdgcn_rcpf((1.f + Eo) * (1.f + Ec));
}

__global__
__attribute__((amdgpu_flat_work_group_size(512, 512), amdgpu_waves_per_eu(2, 2)))
void lstm_fused(const float* __restrict__ X,     // (B,1,T)
                const float* __restrict__ Wp,    // (128,1)
                const float* __restrict__ bp,    // (128)
                const float* __restrict__ Wih1,  // (512,128)
                const float* __restrict__ Whh1,  // (512,128)
                const float* __restrict__ bih1,  // (512)
                const float* __restrict__ bhh1,  // (512)
                const float* __restrict__ Wih2,  // (256,128)
                const float* __restrict__ Whh2,  // (256,64)
                const float* __restrict__ bih2,  // (256)
                const float* __restrict__ bhh2,  // (256)
                const float* __restrict__ W1,    // (128,64)
                const float* __restrict__ b1,    // (128)
                const float* __restrict__ W2,    // (4,128)
                const float* __restrict__ b2,    // (4)
                float* __restrict__ Out) {       // (B,4)
  __shared__ __align__(16) short h1b[2][16][136];  // h1 bf16 dbuf (rows 8..15 stay 0)
  __shared__ __align__(16) short h2b[2][16][72];   // h2 bf16 dbuf
  __shared__ float h2f[8][64];       // final h2 fp32 for FC head
  __shared__ float fc1s[8][132];     // fc1 activations (+4 pad)

  const int tid = threadIdx.x;
  const int ln = tid & 63;
  const int wv = tid >> 6;     // wave 0..7;  0-3 = LSTM2, 4-7 = LSTM1
  const int cl = ln & 15;      // fragment column / A-row
  const int kg = ln >> 4;      // K-group 0..3
  const int r0 = blockIdx.x * BM;
  const bool isL1 = (wv >= 4);
  const int w1 = wv - 4;       // LSTM1 wave index 0..3

  // Weight fragments -- ALIASED between roles (no wave needs both sets).
  // LSTM1 (wv>=4): Wreg[g*4+n][0..3] = Whh1 frags, units 32*w1+16g+cl, gate n.
  // LSTM2 (wv<4):  Wreg[n][0..3] = Wih2 frags; Wreg[4+n][0..1] = Whh2 frags.
  bf16x8 Wreg[8][4];
  float uv[16];   // LSTM1: uv[0..7]=u1*log2e, uv[8..15]=v1*log2e. LSTM2: uv[0..3]=bias*log2e.

  // ---------------- one-time setup (weights pre-scaled by log2e) ----------
  if (isL1) {
#pragma unroll
    for (int g = 0; g < 2; ++g) {
#pragma unroll
      for (int n = 0; n < 4; ++n) {
        const int R = n * 128 + 32 * w1 + 16 * g + cl;
        float u = 0.f, vv = bih1[R] + bhh1[R];
        const float4* Wi4 = (const float4*)(Wih1 + R * 128);
        const float4* Wp4 = (const float4*)Wp;
        const float4* bp4 = (const float4*)bp;
#pragma unroll 4
        for (int d = 0; d < 32; ++d) {
          float4 a = Wi4[d], pw = Wp4[d], qb = bp4[d];
          u  += a.x*pw.x + a.y*pw.y + a.z*pw.z + a.w*pw.w;
          vv += a.x*qb.x + a.y*qb.y + a.z*qb.z + a.w*qb.w;
        }
        uv[g * 4 + n] = u * LOG2E;
        uv[8 + g * 4 + n] = vv * LOG2E;
#pragma unroll
        for (int kf = 0; kf < 4; ++kf) {
          const float4* s4 = (const float4*)(Whh1 + R * 128 + kf * 32 + kg * 8);
          float4 a0 = s4[0], a1 = s4[1];
          bf16x8 fr;
          fr[0]=f2bf(a0.x*LOG2E); fr[1]=f2bf(a0.y*LOG2E);
          fr[2]=f2bf(a0.z*LOG2E); fr[3]=f2bf(a0.w*LOG2E);
          fr[4]=f2bf(a1.x*LOG2E); fr[5]=f2bf(a1.y*LOG2E);
          fr[6]=f2bf(a1.z*LOG2E); fr[7]=f2bf(a1.w*LOG2E);
          Wreg[g * 4 + n][kf] = fr;
        }
      }
    }
  } else {
#pragma unroll
    for (int n = 0; n < 4; ++n) {
      const int R = n * 64 + 16 * wv + cl;
      uv[n] = (bih2[R] + bhh2[R]) * LOG2E;
#pragma unroll
      for (int kf = 0; kf < 4; ++kf) {
        const float4* s4 = (const float4*)(Wih2 + R * 128 + kf * 32 + kg * 8);
        float4 a0 = s4[0], a1 = s4[1];
        bf16x8 fr;
        fr[0]=f2bf(a0.x*LOG2E); fr[1]=f2bf(a0.y*LOG2E);
        fr[2]=f2bf(a0.z*LOG2E); fr[3]=f2bf(a0.w*LOG2E);
        fr[4]=f2bf(a1.x*LOG2E); fr[5]=f2bf(a1.y*LOG2E);
        fr[6]=f2bf(a1.z*LOG2E); fr[7]=f2bf(a1.w*LOG2E);
        Wreg[n][kf] = fr;
      }
#pragma unroll
      for (int kf = 0; kf < 2; ++kf) {
        const float4* s4 = (const float4*)(Whh2 + R * 64 + kf * 32 + kg * 8);
        float4 a0 = s4[0], a1 = s4[1];
        bf16x8 fr;
        fr[0]=f2bf(a0.x*LOG2E); fr[1]=f2bf(a0.y*LOG2E);
        fr[2]=f2bf(a0.z*LOG2E); fr[3]=f2bf(a0.w*LOG2E);
        fr[4]=f2bf(a1.x*LOG2E); fr[5]=f2bf(a1.y*LOG2E);
        fr[6]=f2bf(a1.z*LOG2E); fr[7]=f2bf(a1.w*LOG2E);
        Wreg[4 + n][kf] = fr;
      }
    }
  }

  // zero both h-state buffers (rows 8..15 must stay zero forever)
  for (int i = tid; i < 2 * 16 * 136; i += 512) ((short*)h1b)[i] = 0;
  for (int i = tid; i < 2 * 16 * 72;  i += 512) ((short*)h2b)[i] = 0;
  __syncthreads();

  // per-lane persistent state.
  // LSTM1 wave: 4 cells/lane -> (g0,rA)=cA (g0,rB)=cA2 (g1,rA)=cB (g1,rB)=cB2.
  // LSTM2 wave: 2 cells/lane -> cA2 (rA), cB2 (rB).
  float cA = 0.f, cB = 0.f, cA2 = 0.f, cB2 = 0.f;
  const int rA = (kg < 2) ? kg * 4 : (kg - 2) * 4 + 2;   // redistributed rows
  const int rB = rA + 1;

  float xr[4];
#pragma unroll
  for (int e = 0; e < 4; ++e)
    xr[e] = (isL1 && kg < 2) ? X[(size_t)(r0 + kg * 4 + e) * T_ + 0] : 0.f;

  // ---------------- the scan: iter i -> h1(i) [waves 4-7] + h2(i-1) [0-3] --
  for (int i = 0; i <= T_; ++i) {
    const int cur = i & 1, prv = cur ^ 1;

    if (isL1) {
      if (i < T_) {
        bf16x8 a1[4];
#pragma unroll
        for (int kf = 0; kf < 4; ++kf)
          a1[kf] = *(const bf16x8*)&h1b[prv][cl][kf * 32 + kg * 8];

        f32x4 acc[2][4];
#pragma unroll
        for (int g = 0; g < 2; ++g)
#pragma unroll
          for (int n = 0; n < 4; ++n) {
            f32x4 a;
#pragma unroll
            for (int e = 0; e < 4; ++e)
              a[e] = xr[e] * uv[g * 4 + n] + uv[8 + g * 4 + n];
            acc[g][n] = a;
          }
        __builtin_amdgcn_s_setprio(1);
#pragma unroll
        for (int g = 0; g < 2; ++g)
#pragma unroll
          for (int n = 0; n < 4; ++n)
#pragma unroll
            for (int kf = 0; kf < 4; ++kf)
              acc[g][n] = __builtin_amdgcn_mfma_f32_16x16x32_bf16(
                  a1[kf], Wreg[g * 4 + n][kf], acc[g][n], 0, 0, 0);
        __builtin_amdgcn_s_setprio(0);

        // prefetch x for next step (clamped; rows valid only for kg<2)
        if (kg < 2) {
          const int tn = (i + 1 < T_) ? i + 1 : T_ - 1;
#pragma unroll
          for (int e = 0; e < 4; ++e)
            xr[e] = X[(size_t)(r0 + kg * 4 + e) * T_ + tn];
        }

#pragma unroll
        for (int g = 0; g < 2; ++g) {
          float gA[4], gB[4];
#pragma unroll
          for (int n = 0; n < 4; ++n) {
            float s2 = __shfl_xor(acc[g][n][2], 32);
            float s3 = __shfl_xor(acc[g][n][3], 32);
            gA[n] = (kg < 2) ? acc[g][n][0] : s2;
            gB[n] = (kg < 2) ? acc[g][n][1] : s3;
          }
          float crA = (g == 0) ? cA : cB;
          float crB = (g == 0) ? cA2 : cB2;
          float hA = lstm_cell_s(gA[0], gA[1], gA[2], gA[3], crA);
          float hB = lstm_cell_s(gB[0], gB[1], gB[2], gB[3], crB);
          if (g == 0) { cA = crA; cA2 = crB; } else { cB = crA; cB2 = crB; }

          const int uu = 32 * w1 + 16 * g + cl;
          h1b[cur][rA][uu] = f2bf(hA);
          h1b[cur][rB][uu] = f2bf(hB);
        }
      }
    } else {
      if (i > 0) {
        bf16x8 ah[4], ag[2];
#pragma unroll
        for (int kf = 0; kf < 4; ++kf)
          ah[kf] = *(const bf16x8*)&h1b[prv][cl][kf * 32 + kg * 8];
#pragma unroll
        for (int kf = 0; kf < 2; ++kf)
          ag[kf] = *(const bf16x8*)&h2b[cur][cl][kf * 32 + kg * 8];

        f32x4 acc2[4];
#pragma unroll
        for (int n = 0; n < 4; ++n)
          acc2[n] = (f32x4){uv[n], uv[n], uv[n], uv[n]};
        __builtin_amdgcn_s_setprio(1);
#pragma unroll
        for (int n = 0; n < 4; ++n) {
#pragma unroll
          for (int kf = 0; kf < 2; ++kf)
            acc2[n] = __builtin_amdgcn_mfma_f32_16x16x32_bf16(
                ag[kf], Wreg[4 + n][kf], acc2[n], 0, 0, 0);
#pragma unroll
          for (int kf = 0; kf < 4; ++kf)
            acc2[n] = __builtin_amdgcn_mfma_f32_16x16x32_bf16(
                ah[kf], Wreg[n][kf], acc2[n], 0, 0, 0);
        }
        __builtin_amdgcn_s_setprio(0);

        float gA[4], gB[4];
#pragma unroll
        for (int n = 0; n < 4; ++n) {
          float s2 = __shfl_xor(acc2[n][2], 32);
          float s3 = __shfl_xor(acc2[n][3], 32);
          gA[n] = (kg < 2) ? acc2[n][0] : s2;
          gB[n] = (kg < 2) ? acc2[n][1] : s3;
        }
        float hA = lstm_cell_s(gA[0], gA[1], gA[2], gA[3], cA2);
        float hB = lstm_cell_s(gB[0], gB[1], gB[2], gB[3], cB2);
        const int uu = 16 * wv + cl;
        h2b[prv][rA][uu] = f2bf(hA);   // h2(i-1) lives at parity (i-1)&1 = prv
        h2b[prv][rB][uu] = f2bf(hB);
        if (i == T_) { h2f[rA][uu] = hA; h2f[rB][uu] = hB; }
      }
    }
    __syncthreads();   // publish h1(i) and h2(i-1)
  }

  // ---------------- FC head (fp32) ----------------
  // fc1: (8 x 64) @ (64 x 128) + b1, relu
  {
    const int u = tid & 127, r2 = tid >> 7;   // r2 0..3 -> rows 2r2, 2r2+1
    float a0 = b1[u], a1f = b1[u];
    for (int k = 0; k < 64; ++k) {
      float w = W1[u * 64 + k];
      a0  += h2f[r2 * 2 + 0][k] * w;
      a1f += h2f[r2 * 2 + 1][k] * w;
    }
    fc1s[r2 * 2 + 0][u] = fmaxf(a0, 0.f);
    fc1s[r2 * 2 + 1][u] = fmaxf(a1f, 0.f);
  }
  __syncthreads();
  // fc2: (8 x 128) @ (128 x 4) + b2
  if (tid < 32) {
    const int r = tid >> 2, cls = tid & 3;
    float a = b2[cls];
    for (int k = 0; k < 128; ++k) a += fc1s[r][k] * W2[cls * 128 + k];
    Out[(size_t)(r0 + r) * 4 + cls] = a;
  }
}

extern "C" void kernel_launch(void* const* d_in, const int* in_sizes, int n_in,
                              void* d_out, int out_size, void* d_ws, size_t ws_size,
                              hipStream_t stream) {
  const float* X    = (const float*)d_in[0];
  const float* Wp   = (const float*)d_in[1];
  const float* bp   = (const float*)d_in[2];
  const float* Wih1 = (const float*)d_in[3];
  const float* Whh1 = (const float*)d_in[4];
  const float* bih1 = (const float*)d_in[5];
  const float* bhh1 = (const float*)d_in[6];
  const float* Wih2 = (const float*)d_in[7];
  const float* Whh2 = (const float*)d_in[8];
  const float* bih2 = (const float*)d_in[9];
  const float* bhh2 = (const float*)d_in[10];
  const float* W1   = (const float*)d_in[11];
  const float* b1   = (const float*)d_in[12];
  const float* W2   = (const float*)d_in[13];
  const float* b2   = (const float*)d_in[14];
  float* Out = (float*)d_out;

  hipLaunchKernelGGL(lstm_fused, dim3(NBLK), dim3(512), 0, stream,
                     X, Wp, bp, Wih1, Whh1, bih1, bhh1,
                     Wih2, Whh2, bih2, bhh2, W1, b1, W2, b2, Out);
}